// Round 14
// baseline (166.158 us; speedup 1.0000x reference)
//
#include <hip/hip_runtime.h>
#include <hip/hip_bf16.h>

// A=2048 assets, F=2048 flat dim.
//   q = z@Wq^T + bq ; k = z@Wk^T + bk ; v = z@Wv^T + bv
//   S = (q@k^T)/8 ; P = softmax_rows(S) ; h = P@v
// All GEMMs NT (A[m][k].B[n][k]) bf16 MFMA, f32 accum; v materialized as vT.
// Round 14 = round 13 + ONE structural change: counted-vmcnt 3-buffer K-loop
// (T4). Per iter: STAGE(i+2) -> vmcnt(2*LPS) [tiles i+1,i+2 stay in flight
// ACROSS the barrier] -> s_barrier -> sched_barrier -> COMPUTE ->
// lgkmcnt(0)+sched_barrier -> s_barrier -> sched_barrier. Fence set per
// rule #18 (r6's NaN was missing sched_barrier pins; r7's regression was
// grids/config, fixed since).
//
// ws (32 MB) liveness:
//   [0:8)   zb   (dead after V)     -> P  (bf16, after softmax)
//   [8:16)  Wqb  (dead after QK)    -> vT (bf16, written by V)
//   [16:24) Wkb  (dead after QK)    -> S f32 [16:32)
//   [24:32) Wvb  (dead after V)     -> S cont'd
//   d_out: qb[0:8) + kb[8:16) bf16 (dead after scores) -> final h f32 (PV)

#define AD 2048
#define FD 2048
constexpr float SM_SCALE = 0.125f;   // 64^-0.5

typedef __attribute__((ext_vector_type(8))) short bf16x8;
typedef __attribute__((ext_vector_type(4))) float f32x4;

__device__ __forceinline__ unsigned short f2bf(float f) {
  union { float f; unsigned u; } x; x.f = f;
  unsigned r = x.u + 0x7fffu + ((x.u >> 16) & 1u);   // RNE
  return (unsigned short)(r >> 16);
}

typedef __attribute__((address_space(1))) const void GVOID;
typedef __attribute__((address_space(3))) void LVOID;

__device__ __forceinline__ void gload16(const void* g, void* l) {
  __builtin_amdgcn_global_load_lds((GVOID*)g, (LVOID*)l, 16, 0, 0);
}

struct GemmArgs {
  const void* A;
  const void* B[2];
  const float* bias[2];
  void* out[2];
  float scale;
};

// BK=64, 3-buffer counted-vmcnt pipeline, 8-slot both-sides XOR LDS swizzle
// (conflict-free, measured 0). Wave grid WROWS x WCOLS, wave tile
// (MREP*16) x (NREP*16). XCD-chunked block swizzle (NBM x NBN x NZ grid,
// SBM x SBN superblocks; bm fastest).
// MODE: 0 = f32 row-major (xscale), 1 = bf16 row-major (+bias), 2 = bf16 C^T (+bias)
template<int WROWS, int WCOLS, int MREP, int NREP, int MODE, int W2,
         int NBM, int NBN, int NZ, int SBM, int SBN>
__global__ __launch_bounds__(WROWS*WCOLS*64, W2) void gemm_d(GemmArgs args) {
  constexpr int NT = WROWS * WCOLS * 64;
  constexpr int BM = WROWS * MREP * 16;
  constexpr int BN = WCOLS * NREP * 16;
  constexpr int SA = BM * 8;            // 16B slices per A K-tile (BK=64)
  constexpr int SB = BN * 8;
  static_assert(SA >= NT && SA % NT == 0, "A staging full-coverage");
  static_assert(SB % NT == 0, "B staging full-coverage");
  constexpr int CA  = SA / NT, CB = SB / NT;
  constexpr int LPS = CA + CB;          // VMEM instrs per wave per STAGE
  constexpr int NK  = FD / 64;
  constexpr int NB   = NBM * NBN * NZ;
  constexpr int SBSZ = SBM * SBN;
  constexpr int NSBM = NBM / SBM, NSBN = NBN / SBN;
  static_assert(NB % 8 == 0 && NBM % SBM == 0 && NBN % SBN == 0, "swizzle tiling");

  __shared__ __hip_bfloat16 lA[3][BM * 64];
  __shared__ __hip_bfloat16 lB[3][BN * 64];

  // XCD-chunked bijective swizzle (all divisors compile-time)
  const int bid    = blockIdx.x;
  const int lbid   = (bid & 7) * (NB / 8) + (bid >> 3);
  const int within = lbid % SBSZ;
  const int sb     = lbid / SBSZ;
  const int z      = sb / (NSBM * NSBN);
  const int sbr    = sb % (NSBM * NSBN);
  const int sbm    = sbr % NSBM;        // fastest -> consecutive sbs share B panel
  const int sbn    = sbr / NSBM;
  const int bm     = sbm * SBM + within % SBM;
  const int bn     = sbn * SBN + within / SBM;

  const __hip_bfloat16* __restrict__ A = (const __hip_bfloat16*)args.A;
  const __hip_bfloat16* __restrict__ B = (const __hip_bfloat16*)args.B[z];

  const int t    = threadIdx.x;
  const int lane = t & 63;
  const int wv   = t >> 6;
  const int wr   = wv / WCOLS;
  const int wc   = wv % WCOLS;
  const int fr   = lane & 15;
  const int s2   = lane >> 4;          // logical 16B k-group 0..3 (within K=32)

  f32x4 acc[MREP][NREP] = {};

  // swizzled source column (elements) for slice s: row = s>>3, phys slot = s&7
  // holds logical slot (s&7) ^ (row&7)
  auto scol = [](int s) { return (((s & 7) ^ ((s >> 3) & 7)) * 8); };

  // stage K-tile kt (elems kt*64) into buffer buf
  auto STAGE = [&](int kt, int buf) {
    const int k0 = kt * 64;
    #pragma unroll
    for (int r = 0; r < CA; ++r) {
      const int s = t + r * NT;
      gload16(A + (size_t)(bm * BM + (s >> 3)) * FD + k0 + scol(s), &lA[buf][s * 8]);
    }
    #pragma unroll
    for (int r = 0; r < CB; ++r) {
      const int s = t + r * NT;
      gload16(B + (size_t)(bn * BN + (s >> 3)) * FD + k0 + scol(s), &lB[buf][s * 8]);
    }
  };

  auto COMPUTE = [&](int buf) {
    #pragma unroll
    for (int kk = 0; kk < 2; ++kk) {       // two K=32 sub-steps per BK=64 tile
      const int ls = s2 + 4 * kk;          // logical slot 0..7
      bf16x8 af[MREP], bfr[NREP];
      #pragma unroll
      for (int m = 0; m < MREP; ++m) {
        const int row = wr * (MREP * 16) + m * 16 + fr;
        af[m] = *reinterpret_cast<const bf16x8*>(
            &lA[buf][row * 64 + ((ls ^ (row & 7)) * 8)]);
      }
      #pragma unroll
      for (int n = 0; n < NREP; ++n) {
        const int row = wc * (NREP * 16) + n * 16 + fr;
        bfr[n] = *reinterpret_cast<const bf16x8*>(
            &lB[buf][row * 64 + ((ls ^ (row & 7)) * 8)]);
      }
      #pragma unroll
      for (int m = 0; m < MREP; ++m)
        #pragma unroll
        for (int n = 0; n < NREP; ++n)
          acc[m][n] = __builtin_amdgcn_mfma_f32_16x16x32_bf16(af[m], bfr[n], acc[m][n], 0, 0, 0);
    }
  };

  // prologue: tiles 0,1 in flight (2*LPS outstanding)
  STAGE(0, 0); STAGE(1, 1);
  int cur = 0;
  for (int i = 0; i < NK - 2; ++i) {
    STAGE(i + 2, cur == 0 ? 2 : cur - 1);   // buffer (cur+2)%3; now 3*LPS in flight
    asm volatile("s_waitcnt vmcnt(%0)" :: "i"(2 * LPS) : "memory");  // tile i landed
    __builtin_amdgcn_s_barrier();           // all waves' tile-i writes visible
    __builtin_amdgcn_sched_barrier(0);      // no ds_read hoists above (rule #18)
    COMPUTE(cur);
    asm volatile("s_waitcnt lgkmcnt(0)" ::: "memory");  // own frag reads retired
    __builtin_amdgcn_sched_barrier(0);
    __builtin_amdgcn_s_barrier();           // all waves done reading buf[cur]
    __builtin_amdgcn_sched_barrier(0);      // next STAGE can't hoist above
    cur = cur == 2 ? 0 : cur + 1;
  }
  // tail: tiles NK-2, NK-1 (no restaging -> no post-read barriers needed)
  asm volatile("s_waitcnt vmcnt(%0)" :: "i"(LPS) : "memory");
  __builtin_amdgcn_s_barrier();
  __builtin_amdgcn_sched_barrier(0);
  COMPUTE(cur);
  cur = cur == 2 ? 0 : cur + 1;
  asm volatile("s_waitcnt vmcnt(0)" ::: "memory");
  __builtin_amdgcn_s_barrier();
  __builtin_amdgcn_sched_barrier(0);
  COMPUTE(cur);

  // Epilogue. C/D mapping (m89-verified): col = lane&15, row = (lane>>4)*4 + j
  const float scale = args.scale;
  const float* __restrict__ bias = args.bias[z];
  const int row0 = bm * BM + wr * (MREP * 16) + (lane >> 4) * 4;
  const int col0 = bn * BN + wc * (NREP * 16) + fr;

  if constexpr (MODE == 0) {
    float* __restrict__ out = (float*)args.out[z];
    #pragma unroll
    for (int m = 0; m < MREP; ++m)
      #pragma unroll
      for (int n = 0; n < NREP; ++n) {
        const int cg = col0 + n * 16;
        #pragma unroll
        for (int j = 0; j < 4; ++j)
          out[(size_t)(row0 + m * 16 + j) * FD + cg] = acc[m][n][j] * scale;
      }
  } else if constexpr (MODE == 1) {
    __hip_bfloat16* __restrict__ out = (__hip_bfloat16*)args.out[z];
    #pragma unroll
    for (int m = 0; m < MREP; ++m)
      #pragma unroll
      for (int n = 0; n < NREP; ++n) {
        const int cg = col0 + n * 16;
        const float badd = bias[cg];
        #pragma unroll
        for (int j = 0; j < 4; ++j) {
          unsigned short b16 = f2bf(acc[m][n][j] + badd);
          out[(size_t)(row0 + m * 16 + j) * FD + cg] = *reinterpret_cast<__hip_bfloat16*>(&b16);
        }
      }
  } else { // MODE == 2: store C^T -> vT[f][a]; 4 consecutive rows = one 8B store
    __hip_bfloat16* __restrict__ out = (__hip_bfloat16*)args.out[z];
    #pragma unroll
    for (int m = 0; m < MREP; ++m)
      #pragma unroll
      for (int n = 0; n < NREP; ++n) {
        const int cg = col0 + n * 16;   // F index -> row of vT
        const int rg = row0 + m * 16;   // asset index -> col of vT
        const float badd = bias[cg];
        ushort4 pk;
        pk.x = f2bf(acc[m][n][0] + badd);
        pk.y = f2bf(acc[m][n][1] + badd);
        pk.z = f2bf(acc[m][n][2] + badd);
        pk.w = f2bf(acc[m][n][3] + badd);
        *reinterpret_cast<ushort4*>(out + (size_t)cg * AD + rg) = pk;
      }
  }
}

// convert z, Wq, Wk, Wv (f32) -> bf16 [zb | Wqb | Wkb | Wvb], 4M elems each
__global__ __launch_bounds__(256) void cvt_bf16(const float* __restrict__ z,
                                                const float* __restrict__ wq,
                                                const float* __restrict__ wk,
                                                const float* __restrict__ wv,
                                                __hip_bfloat16* __restrict__ dst) {
  const size_t NITEM = (size_t)4 * 4096 * 1024 / 8;
  const size_t step = (size_t)gridDim.x * blockDim.x;
  for (size_t idx = (size_t)blockIdx.x * blockDim.x + threadIdx.x; idx < NITEM; idx += step) {
    const int ten = (int)(idx >> 19);
    const size_t off = (idx & ((1u << 19) - 1)) * 8;
    const float* src = (ten == 0) ? z : (ten == 1) ? wq : (ten == 2) ? wk : wv;
    const float4 a = *reinterpret_cast<const float4*>(src + off);
    const float4 b = *reinterpret_cast<const float4*>(src + off + 4);
    union { unsigned short us[8]; int4 v; } pk;
    pk.us[0] = f2bf(a.x); pk.us[1] = f2bf(a.y); pk.us[2] = f2bf(a.z); pk.us[3] = f2bf(a.w);
    pk.us[4] = f2bf(b.x); pk.us[5] = f2bf(b.y); pk.us[6] = f2bf(b.z); pk.us[7] = f2bf(b.w);
    *reinterpret_cast<int4*>(dst + (size_t)ten * 4096 * 1024 + off) = pk.v;
  }
}

__global__ __launch_bounds__(256) void softmax_rows(const float* __restrict__ S,
                                                    __hip_bfloat16* __restrict__ P) {
  const int row = blockIdx.x;
  const int t = threadIdx.x;
  const float* s = S + (size_t)row * AD + t * 8;
  const float4 v0 = *reinterpret_cast<const float4*>(s);
  const float4 v1 = *reinterpret_cast<const float4*>(s + 4);
  float vals[8] = {v0.x, v0.y, v0.z, v0.w, v1.x, v1.y, v1.z, v1.w};

  float m = vals[0];
  #pragma unroll
  for (int j = 1; j < 8; ++j) m = fmaxf(m, vals[j]);
  #pragma unroll
  for (int off = 32; off >= 1; off >>= 1) m = fmaxf(m, __shfl_xor(m, off));

  __shared__ float redm[4], reds[4];
  if ((t & 63) == 0) redm[t >> 6] = m;
  __syncthreads();
  m = fmaxf(fmaxf(redm[0], redm[1]), fmaxf(redm[2], redm[3]));

  float e[8];
  float sum = 0.f;
  #pragma unroll
  for (int j = 0; j < 8; ++j) { e[j] = __expf(vals[j] - m); sum += e[j]; }
  #pragma unroll
  for (int off = 32; off >= 1; off >>= 1) sum += __shfl_xor(sum, off);
  if ((t & 63) == 0) reds[t >> 6] = sum;
  __syncthreads();
  sum = reds[0] + reds[1] + reds[2] + reds[3];
  const float inv = 1.f / sum;

  union { unsigned short us[8]; int4 v; } pk;
  #pragma unroll
  for (int j = 0; j < 8; ++j) pk.us[j] = f2bf(e[j] * inv);
  *reinterpret_cast<int4*>(P + (size_t)row * AD + t * 8) = pk.v;
}

extern "C" void kernel_launch(void* const* d_in, const int* in_sizes, int n_in,
                              void* d_out, int out_size, void* d_ws, size_t ws_size,
                              hipStream_t stream) {
  const float* z  = (const float*)d_in[0];
  const float* Wq = (const float*)d_in[1];
  const float* bq = (const float*)d_in[2];
  const float* Wk = (const float*)d_in[3];
  const float* bk = (const float*)d_in[4];
  const float* Wv = (const float*)d_in[5];
  const float* bv = (const float*)d_in[6];

  char* ws = (char*)d_ws;
  const size_t MB8 = (size_t)8 * 1024 * 1024;
  __hip_bfloat16* zb  = (__hip_bfloat16*)(ws);            // dead after V
  __hip_bfloat16* Wqb = (__hip_bfloat16*)(ws + MB8);      // dead after QK
  __hip_bfloat16* Wkb = (__hip_bfloat16*)(ws + 2*MB8);    // dead after QK
  __hip_bfloat16* Wvb = (__hip_bfloat16*)(ws + 3*MB8);    // dead after V
  __hip_bfloat16* vT  = (__hip_bfloat16*)(ws + MB8);      // over Wqb
  float*          S   = (float*)(ws + 2*MB8);             // over Wkb+Wvb (16MB)
  __hip_bfloat16* P   = (__hip_bfloat16*)(ws);            // over zb
  __hip_bfloat16* qb  = (__hip_bfloat16*)d_out;           // d_out scratch [0:8)MB
  __hip_bfloat16* kb  = (__hip_bfloat16*)d_out + (size_t)AD * FD;  // [8:16)MB

  // 0) convert all four tensors to bf16
  cvt_bf16<<<dim3(2048), dim3(256), 0, stream>>>(z, Wq, Wk, Wv, (__hip_bfloat16*)ws);

  // 1) fused QK (pure bf16): (2,4,4,2) 128^2 BK=64, 512 blocks, XCD-chunked 4x4
  {
    GemmArgs a;
    a.A = zb;
    a.B[0] = Wqb;  a.B[1] = Wkb;
    a.bias[0] = bq; a.bias[1] = bk;
    a.out[0] = qb;  a.out[1] = kb;
    a.scale = 1.0f;
    gemm_d<2, 4, 4, 2, 1, 2, 16, 16, 2, 4, 4>
        <<<dim3(512), dim3(512), 0, stream>>>(a);
  }
  // 2) V (pure bf16): (4,2,2,2) 128x64 BK=64, 512 blocks, XCD-chunked 4x8 -> vT
  {
    GemmArgs a = {};
    a.A = zb;
    a.B[0] = Wvb;
    a.bias[0] = bv;
    a.out[0] = vT;
    a.scale = 1.0f;
    gemm_d<4, 2, 2, 2, 2, 2, 16, 32, 1, 4, 8>
        <<<dim3(512), dim3(512), 0, stream>>>(a);
  }
  // 3) scores = (qb @ kb^T)/8 -> f32 S over Wkb+Wvb ; 512 blocks
  {
    GemmArgs a = {};
    a.A = qb;
    a.B[0] = kb;
    a.bias[0] = nullptr;
    a.out[0] = S;
    a.scale = SM_SCALE;
    gemm_d<4, 2, 2, 2, 0, 2, 16, 32, 1, 4, 8>
        <<<dim3(512), dim3(512), 0, stream>>>(a);
  }
  // 4) row softmax -> P bf16 (over zb)
  softmax_rows<<<dim3(AD), dim3(256), 0, stream>>>(S, P);
  // 5) h = P @ vT^T -> f32 d_out ; 512 blocks
  {
    GemmArgs a = {};
    a.A = P;
    a.B[0] = vT;
    a.bias[0] = nullptr;
    a.out[0] = d_out;
    a.scale = 1.0f;
    gemm_d<4, 2, 2, 2, 0, 2, 16, 32, 1, 4, 8>
        <<<dim3(512), dim3(512), 0, stream>>>(a);
  }
}

// Round 15
// 141.288 us; speedup vs baseline: 1.1760x; 1.1760x over previous
//
#include <hip/hip_runtime.h>
#include <hip/hip_bf16.h>

// A=2048 assets, F=2048 flat dim.
//   q = z@Wq^T + bq ; k = z@Wk^T + bk ; v = z@Wv^T + bv
//   S = (q@k^T)/8 ; P = softmax_rows(S) ; h = P@v
// All GEMMs NT (A[m][k].B[n][k]) bf16 MFMA, f32 accum; v materialized as vT.
// TERMINAL STATE (= round-13 measured best, 140.76 us):
//   - 2-phase dbuf K-loop (STAGE next -> COMPUTE cur -> one __syncthreads).
//     Counted-vmcnt/8-phase escapes falsified 3x at this geometry (r7/r14;
//     m232 quadrant) - the barrier drain is structural here.
//   - BK=64, 8-slot both-sides XOR LDS swizzle (bank conflicts measured 0).
//   - global_load_lds width-16 staging, pre-swizzled global source (rule #21).
//   - XCD-chunked bijective block swizzle, 4MB-L2-fit superblocks.
//   - pure-bf16 operands via one cvt pass (f32-B staging measured -30%).
//
// ws (32 MB) liveness:
//   [0:8)   zb   (dead after V)     -> P  (bf16, after softmax)
//   [8:16)  Wqb  (dead after QK)    -> vT (bf16, written by V)
//   [16:24) Wkb  (dead after QK)    -> S f32 [16:32)
//   [24:32) Wvb  (dead after V)     -> S cont'd
//   d_out: qb[0:8) + kb[8:16) bf16 (dead after scores) -> final h f32 (PV)

#define AD 2048
#define FD 2048
constexpr float SM_SCALE = 0.125f;   // 64^-0.5

typedef __attribute__((ext_vector_type(8))) short bf16x8;
typedef __attribute__((ext_vector_type(4))) float f32x4;

__device__ __forceinline__ unsigned short f2bf(float f) {
  union { float f; unsigned u; } x; x.f = f;
  unsigned r = x.u + 0x7fffu + ((x.u >> 16) & 1u);   // RNE
  return (unsigned short)(r >> 16);
}

typedef __attribute__((address_space(1))) const void GVOID;
typedef __attribute__((address_space(3))) void LVOID;

__device__ __forceinline__ void gload16(const void* g, void* l) {
  __builtin_amdgcn_global_load_lds((GVOID*)g, (LVOID*)l, 16, 0, 0);
}

struct GemmArgs {
  const void* A;
  const void* B[2];
  const float* bias[2];
  void* out[2];
  float scale;
};

// BK=64, dbuf LDS, 8-slot both-sides XOR swizzle (conflict-free, measured 0).
// Wave grid WROWS x WCOLS, wave tile (MREP*16) x (NREP*16).
// Block-index decomposition: NBM x NBN x NZ logical blocks, XCD-chunked with
// SBM x SBN superblocks (bm fastest within; sbm fastest across superblocks).
// MODE: 0 = f32 row-major (xscale), 1 = bf16 row-major (+bias), 2 = bf16 C^T (+bias)
template<int WROWS, int WCOLS, int MREP, int NREP, int MODE, int W2,
         int NBM, int NBN, int NZ, int SBM, int SBN>
__global__ __launch_bounds__(WROWS*WCOLS*64, W2) void gemm_d(GemmArgs args) {
  constexpr int NT = WROWS * WCOLS * 64;
  constexpr int BM = WROWS * MREP * 16;
  constexpr int BN = WCOLS * NREP * 16;
  constexpr int SA = BM * 8;            // 16B slices per A K-tile (BK=64)
  constexpr int SB = BN * 8;
  static_assert(SA >= NT && SA % NT == 0, "A staging full-coverage");
  static_assert(SB % NT == 0, "B staging full-coverage");
  constexpr int NB   = NBM * NBN * NZ;
  constexpr int SBSZ = SBM * SBN;
  constexpr int NSBM = NBM / SBM, NSBN = NBN / SBN;
  static_assert(NB % 8 == 0 && NBM % SBM == 0 && NBN % SBN == 0, "swizzle tiling");

  __shared__ __hip_bfloat16 lA[2][BM * 64];
  __shared__ __hip_bfloat16 lB[2][BN * 64];

  // XCD-chunked bijective swizzle (all divisors compile-time)
  const int bid    = blockIdx.x;
  const int lbid   = (bid & 7) * (NB / 8) + (bid >> 3);
  const int within = lbid % SBSZ;
  const int sb     = lbid / SBSZ;
  const int z      = sb / (NSBM * NSBN);
  const int sbr    = sb % (NSBM * NSBN);
  const int sbm    = sbr % NSBM;        // fastest -> consecutive sbs share B panel
  const int sbn    = sbr / NSBM;
  const int bm     = sbm * SBM + within % SBM;
  const int bn     = sbn * SBN + within / SBM;

  const __hip_bfloat16* __restrict__ A = (const __hip_bfloat16*)args.A;
  const __hip_bfloat16* __restrict__ B = (const __hip_bfloat16*)args.B[z];

  const int t    = threadIdx.x;
  const int lane = t & 63;
  const int wv   = t >> 6;
  const int wr   = wv / WCOLS;
  const int wc   = wv % WCOLS;
  const int fr   = lane & 15;
  const int s2   = lane >> 4;          // logical 16B k-group 0..3 (within K=32)

  f32x4 acc[MREP][NREP] = {};

  // swizzled source column (elements) for slice s: row = s>>3, phys slot = s&7
  // holds logical slot (s&7) ^ (row&7)
  auto scol = [](int s) { return (((s & 7) ^ ((s >> 3) & 7)) * 8); };

  auto STAGE = [&](int k0, int buf) {
    #pragma unroll
    for (int r = 0; r < SA / NT; ++r) {
      const int s = t + r * NT;
      gload16(A + (size_t)(bm * BM + (s >> 3)) * FD + k0 + scol(s), &lA[buf][s * 8]);
    }
    #pragma unroll
    for (int r = 0; r < SB / NT; ++r) {
      const int s = t + r * NT;
      gload16(B + (size_t)(bn * BN + (s >> 3)) * FD + k0 + scol(s), &lB[buf][s * 8]);
    }
  };

  auto COMPUTE = [&](int buf) {
    #pragma unroll
    for (int kk = 0; kk < 2; ++kk) {       // two K=32 sub-steps per BK=64 tile
      const int ls = s2 + 4 * kk;          // logical slot 0..7
      bf16x8 af[MREP], bfr[NREP];
      #pragma unroll
      for (int m = 0; m < MREP; ++m) {
        const int row = wr * (MREP * 16) + m * 16 + fr;
        af[m] = *reinterpret_cast<const bf16x8*>(
            &lA[buf][row * 64 + ((ls ^ (row & 7)) * 8)]);
      }
      #pragma unroll
      for (int n = 0; n < NREP; ++n) {
        const int row = wc * (NREP * 16) + n * 16 + fr;
        bfr[n] = *reinterpret_cast<const bf16x8*>(
            &lB[buf][row * 64 + ((ls ^ (row & 7)) * 8)]);
      }
      #pragma unroll
      for (int m = 0; m < MREP; ++m)
        #pragma unroll
        for (int n = 0; n < NREP; ++n)
          acc[m][n] = __builtin_amdgcn_mfma_f32_16x16x32_bf16(af[m], bfr[n], acc[m][n], 0, 0, 0);
    }
  };

  STAGE(0, 0);
  __syncthreads();
  int cur = 0;
  for (int k0 = 64; k0 < FD; k0 += 64) {
    STAGE(k0, cur ^ 1);     // prefetch next tile (in flight during COMPUTE)
    COMPUTE(cur);
    __syncthreads();        // drains prefetch + all frag reads of cur
    cur ^= 1;
  }
  COMPUTE(cur);

  // Epilogue. C/D mapping (m89-verified): col = lane&15, row = (lane>>4)*4 + j
  const float scale = args.scale;
  const float* __restrict__ bias = args.bias[z];
  const int row0 = bm * BM + wr * (MREP * 16) + (lane >> 4) * 4;
  const int col0 = bn * BN + wc * (NREP * 16) + fr;

  if constexpr (MODE == 0) {
    float* __restrict__ out = (float*)args.out[z];
    #pragma unroll
    for (int m = 0; m < MREP; ++m)
      #pragma unroll
      for (int n = 0; n < NREP; ++n) {
        const int cg = col0 + n * 16;
        #pragma unroll
        for (int j = 0; j < 4; ++j)
          out[(size_t)(row0 + m * 16 + j) * FD + cg] = acc[m][n][j] * scale;
      }
  } else if constexpr (MODE == 1) {
    __hip_bfloat16* __restrict__ out = (__hip_bfloat16*)args.out[z];
    #pragma unroll
    for (int m = 0; m < MREP; ++m)
      #pragma unroll
      for (int n = 0; n < NREP; ++n) {
        const int cg = col0 + n * 16;
        const float badd = bias[cg];
        #pragma unroll
        for (int j = 0; j < 4; ++j) {
          unsigned short b16 = f2bf(acc[m][n][j] + badd);
          out[(size_t)(row0 + m * 16 + j) * FD + cg] = *reinterpret_cast<__hip_bfloat16*>(&b16);
        }
      }
  } else { // MODE == 2: store C^T -> vT[f][a]; 4 consecutive rows = one 8B store
    __hip_bfloat16* __restrict__ out = (__hip_bfloat16*)args.out[z];
    #pragma unroll
    for (int m = 0; m < MREP; ++m)
      #pragma unroll
      for (int n = 0; n < NREP; ++n) {
        const int cg = col0 + n * 16;   // F index -> row of vT
        const int rg = row0 + m * 16;   // asset index -> col of vT
        const float badd = bias[cg];
        ushort4 pk;
        pk.x = f2bf(acc[m][n][0] + badd);
        pk.y = f2bf(acc[m][n][1] + badd);
        pk.z = f2bf(acc[m][n][2] + badd);
        pk.w = f2bf(acc[m][n][3] + badd);
        *reinterpret_cast<ushort4*>(out + (size_t)cg * AD + rg) = pk;
      }
  }
}

// convert z, Wq, Wk, Wv (f32) -> bf16 [zb | Wqb | Wkb | Wvb], 4M elems each
__global__ __launch_bounds__(256) void cvt_bf16(const float* __restrict__ z,
                                                const float* __restrict__ wq,
                                                const float* __restrict__ wk,
                                                const float* __restrict__ wv,
                                                __hip_bfloat16* __restrict__ dst) {
  const size_t NITEM = (size_t)4 * 4096 * 1024 / 8;
  const size_t step = (size_t)gridDim.x * blockDim.x;
  for (size_t idx = (size_t)blockIdx.x * blockDim.x + threadIdx.x; idx < NITEM; idx += step) {
    const int ten = (int)(idx >> 19);
    const size_t off = (idx & ((1u << 19) - 1)) * 8;
    const float* src = (ten == 0) ? z : (ten == 1) ? wq : (ten == 2) ? wk : wv;
    const float4 a = *reinterpret_cast<const float4*>(src + off);
    const float4 b = *reinterpret_cast<const float4*>(src + off + 4);
    union { unsigned short us[8]; int4 v; } pk;
    pk.us[0] = f2bf(a.x); pk.us[1] = f2bf(a.y); pk.us[2] = f2bf(a.z); pk.us[3] = f2bf(a.w);
    pk.us[4] = f2bf(b.x); pk.us[5] = f2bf(b.y); pk.us[6] = f2bf(b.z); pk.us[7] = f2bf(b.w);
    *reinterpret_cast<int4*>(dst + (size_t)ten * 4096 * 1024 + off) = pk.v;
  }
}

__global__ __launch_bounds__(256) void softmax_rows(const float* __restrict__ S,
                                                    __hip_bfloat16* __restrict__ P) {
  const int row = blockIdx.x;
  const int t = threadIdx.x;
  const float* s = S + (size_t)row * AD + t * 8;
  const float4 v0 = *reinterpret_cast<const float4*>(s);
  const float4 v1 = *reinterpret_cast<const float4*>(s + 4);
  float vals[8] = {v0.x, v0.y, v0.z, v0.w, v1.x, v1.y, v1.z, v1.w};

  float m = vals[0];
  #pragma unroll
  for (int j = 1; j < 8; ++j) m = fmaxf(m, vals[j]);
  #pragma unroll
  for (int off = 32; off >= 1; off >>= 1) m = fmaxf(m, __shfl_xor(m, off));

  __shared__ float redm[4], reds[4];
  if ((t & 63) == 0) redm[t >> 6] = m;
  __syncthreads();
  m = fmaxf(fmaxf(redm[0], redm[1]), fmaxf(redm[2], redm[3]));

  float e[8];
  float sum = 0.f;
  #pragma unroll
  for (int j = 0; j < 8; ++j) { e[j] = __expf(vals[j] - m); sum += e[j]; }
  #pragma unroll
  for (int off = 32; off >= 1; off >>= 1) sum += __shfl_xor(sum, off);
  if ((t & 63) == 0) reds[t >> 6] = sum;
  __syncthreads();
  sum = reds[0] + reds[1] + reds[2] + reds[3];
  const float inv = 1.f / sum;

  union { unsigned short us[8]; int4 v; } pk;
  #pragma unroll
  for (int j = 0; j < 8; ++j) pk.us[j] = f2bf(e[j] * inv);
  *reinterpret_cast<int4*>(P + (size_t)row * AD + t * 8) = pk.v;
}

extern "C" void kernel_launch(void* const* d_in, const int* in_sizes, int n_in,
                              void* d_out, int out_size, void* d_ws, size_t ws_size,
                              hipStream_t stream) {
  const float* z  = (const float*)d_in[0];
  const float* Wq = (const float*)d_in[1];
  const float* bq = (const float*)d_in[2];
  const float* Wk = (const float*)d_in[3];
  const float* bk = (const float*)d_in[4];
  const float* Wv = (const float*)d_in[5];
  const float* bv = (const float*)d_in[6];

  char* ws = (char*)d_ws;
  const size_t MB8 = (size_t)8 * 1024 * 1024;
  __hip_bfloat16* zb  = (__hip_bfloat16*)(ws);            // dead after V
  __hip_bfloat16* Wqb = (__hip_bfloat16*)(ws + MB8);      // dead after QK
  __hip_bfloat16* Wkb = (__hip_bfloat16*)(ws + 2*MB8);    // dead after QK
  __hip_bfloat16* Wvb = (__hip_bfloat16*)(ws + 3*MB8);    // dead after V
  __hip_bfloat16* vT  = (__hip_bfloat16*)(ws + MB8);      // over Wqb
  float*          S   = (float*)(ws + 2*MB8);             // over Wkb+Wvb (16MB)
  __hip_bfloat16* P   = (__hip_bfloat16*)(ws);            // over zb
  __hip_bfloat16* qb  = (__hip_bfloat16*)d_out;           // d_out scratch [0:8)MB
  __hip_bfloat16* kb  = (__hip_bfloat16*)d_out + (size_t)AD * FD;  // [8:16)MB

  // 0) convert all four tensors to bf16
  cvt_bf16<<<dim3(2048), dim3(256), 0, stream>>>(z, Wq, Wk, Wv, (__hip_bfloat16*)ws);

  // 1) fused QK (pure bf16): (2,4,4,2) 128^2 BK=64, 512 blocks, XCD-chunked 4x4
  {
    GemmArgs a;
    a.A = zb;
    a.B[0] = Wqb;  a.B[1] = Wkb;
    a.bias[0] = bq; a.bias[1] = bk;
    a.out[0] = qb;  a.out[1] = kb;
    a.scale = 1.0f;
    gemm_d<2, 4, 4, 2, 1, 2, 16, 16, 2, 4, 4>
        <<<dim3(512), dim3(512), 0, stream>>>(a);
  }
  // 2) V (pure bf16): (4,2,2,2) 128x64 BK=64, 512 blocks, XCD-chunked 4x8 -> vT
  {
    GemmArgs a = {};
    a.A = zb;
    a.B[0] = Wvb;
    a.bias[0] = bv;
    a.out[0] = vT;
    a.scale = 1.0f;
    gemm_d<4, 2, 2, 2, 2, 2, 16, 32, 1, 4, 8>
        <<<dim3(512), dim3(512), 0, stream>>>(a);
  }
  // 3) scores = (qb @ kb^T)/8 -> f32 S over Wkb+Wvb ; 512 blocks
  {
    GemmArgs a = {};
    a.A = qb;
    a.B[0] = kb;
    a.bias[0] = nullptr;
    a.out[0] = S;
    a.scale = SM_SCALE;
    gemm_d<4, 2, 2, 2, 0, 2, 16, 32, 1, 4, 8>
        <<<dim3(512), dim3(512), 0, stream>>>(a);
  }
  // 4) row softmax -> P bf16 (over zb)
  softmax_rows<<<dim3(AD), dim3(256), 0, stream>>>(S, P);
  // 5) h = P @ vT^T -> f32 d_out ; 512 blocks
  {
    GemmArgs a = {};
    a.A = P;
    a.B[0] = vT;
    a.bias[0] = nullptr;
    a.out[0] = d_out;
    a.scale = 1.0f;
    gemm_d<4, 2, 2, 2, 0, 2, 16, 32, 1, 4, 8>
        <<<dim3(512), dim3(512), 0, stream>>>(a);
  }
}